// Round 1
// 748.423 us; speedup vs baseline: 1.8689x; 1.8689x over previous
//
#include <hip/hip_runtime.h>

// Attention (B=4, T=2048, dim=2048, H=16, hd=128) on gfx950.
// Pipeline: cast->bf16 | QKV gemms (MFMA, A*B^T) | RoPE | flash attention | out gemm.
// R3: flash rewritten: 8-wave blocks (256 q-rows), KVBLK=64, double-buffered K/V with
//     prefetch (2-phase pipeline, one barrier/iter), wave-private P buffer, Q direct
//     global->reg, LDS-staged coalesced 16B output stores (was 2B scatter = 16x write
//     amplification), setprio around MFMA clusters.
// Workspace layout (needs 192 MiB):
//   xb[2^24] wqb wkb wvb wob[2^22 each] qb[2^24] kb[2^24] vtb[2^24] aout[2^24]  (all bf16)

using floatx4  = __attribute__((ext_vector_type(4))) float;
using short8   = __attribute__((ext_vector_type(8))) short;
using ushortx4 = __attribute__((ext_vector_type(4))) unsigned short;

#define DEVFN static __device__ __forceinline__

DEVFN unsigned short f2bf(float f) {          // RNE float->bf16
  unsigned u = __builtin_bit_cast(unsigned, f);
  u += 0x7fffu + ((u >> 16) & 1u);
  return (unsigned short)(u >> 16);
}
DEVFN float bf2f(unsigned short h) {
  return __builtin_bit_cast(float, ((unsigned)h) << 16);
}

DEVFN void async_cp16(const unsigned short* g, unsigned short* l) {
  __builtin_amdgcn_global_load_lds(
      (const __attribute__((address_space(1))) void*)g,
      (__attribute__((address_space(3))) void*)l,
      16, 0, 0);
}

// ---------------- cast fp32 -> bf16 (vectorized) ----------------
__global__ __launch_bounds__(256) void cast_kernel(const float4* __restrict__ in,
                                                   ushortx4* __restrict__ out) {
  long u = (long)blockIdx.x * 256 + threadIdx.x;
  float4 v = in[u];
  out[u] = (ushortx4){f2bf(v.x), f2bf(v.y), f2bf(v.z), f2bf(v.w)};
}

// ---------------- RoPE in-place on Q,K [64][2048][128] bf16 ----------------
__global__ __launch_bounds__(256) void rope_kernel(unsigned short* __restrict__ Q,
                                                   unsigned short* __restrict__ K,
                                                   const float* __restrict__ pos) {
  long idx = (long)blockIdx.x * 256 + threadIdx.x;   // 2^24 threads
  unsigned short* arr = (idx >> 23) ? K : Q;
  long rem = idx & ((1L << 23) - 1);
  long row = rem >> 6;          // bh*2048 + t
  int j = (int)(rem & 63);      // pair index 0..63
  int t = (int)(row & 2047);
  // freq_j = 10000^(-j/64) = exp2(-j * log2(10000)/64)
  float ang = pos[t] * exp2f(-0.20762051f * (float)j);
  float s = sinf(ang), c = cosf(ang);
  unsigned short* base = arr + (row << 7);
  float x1 = bf2f(base[j]), x2 = bf2f(base[j + 64]);
  base[j]      = f2bf(x1 * c - x2 * s);
  base[j + 64] = f2bf(x2 * c + x1 * s);
}

// ---------------- GEMM: C[m,n] = sum_k A[m,k]*B[n,k] + bias[n] ----------------
// M=8192 N=2048 K=2048. 128x128 tile, BK=64, 4 waves (2x2 of 64x64), mfma 16x16x32.
// 1D grid 1024, XCD swizzle: xcd = bid&7 owns m-tiles xcd*8..xcd*8+7 (A L2-resident).
// LDS XOR-swizzle: phys_chunk = chunk ^ (row&7)  (8 chunks of 16B per 64-elem row).
// MODE 0: bf16 out [B,H,T,hd]   (Q,K pre-RoPE)
// MODE 1: bf16 out [B,H,hd,T]   (V transposed)
// MODE 2: fp32 out [M,N]        (final projection)
template <int MODE>
__global__ __launch_bounds__(256) void gemm_bt(const unsigned short* __restrict__ A,
                                               const unsigned short* __restrict__ Bw,
                                               const float* __restrict__ bias,
                                               void* __restrict__ Cout) {
  constexpr int K = 2048;
  __shared__ __align__(16) unsigned short lds_a[128 * 64];
  __shared__ __align__(16) unsigned short lds_b[128 * 64];
  const int tid = threadIdx.x;
  const int wave = tid >> 6, lane = tid & 63;
  const int ln15 = lane & 15, quad = lane >> 4;
  const int wr = wave >> 1, wc = wave & 1;
  const int bid = blockIdx.x;
  const int xcd = bid & 7, sl = bid >> 3;          // sl in [0,128)
  const int m0 = (xcd * 8 + (sl & 7)) * 128;       // 8 m-tiles per XCD
  const int n0 = (sl >> 3) * 128;                  // 16 n-tiles

  floatx4 acc[4][4];
#pragma unroll
  for (int i = 0; i < 4; ++i)
#pragma unroll
    for (int j = 0; j < 4; ++j) acc[i][j] = (floatx4){0.f, 0.f, 0.f, 0.f};

  for (int k0 = 0; k0 < K; k0 += 64) {
    __syncthreads();
#pragma unroll
    for (int j = 0; j < 4; ++j) {   // A tile: 1024 16B units
      int u = j * 256 + tid;
      int row = u >> 3;
      int c = (u & 7) ^ (row & 7);
      async_cp16(A + (long)(m0 + row) * K + (k0 + c * 8),
                 lds_a + (j * 256 + wave * 64) * 8);
    }
#pragma unroll
    for (int j = 0; j < 4; ++j) {   // B tile
      int u = j * 256 + tid;
      int row = u >> 3;
      int c = (u & 7) ^ (row & 7);
      async_cp16(Bw + (long)(n0 + row) * K + (k0 + c * 8),
                 lds_b + (j * 256 + wave * 64) * 8);
    }
    asm volatile("s_waitcnt vmcnt(0)" ::: "memory");
    __syncthreads();
#pragma unroll
    for (int ks = 0; ks < 2; ++ks) {
      short8 af[4], bf[4];
#pragma unroll
      for (int mi = 0; mi < 4; ++mi) {
        int row = wr * 64 + mi * 16 + ln15;
        int phys = (ks * 4 + quad) ^ (row & 7);
        af[mi] = *(const short8*)(lds_a + row * 64 + phys * 8);
      }
#pragma unroll
      for (int ni = 0; ni < 4; ++ni) {
        int row = wc * 64 + ni * 16 + ln15;
        int phys = (ks * 4 + quad) ^ (row & 7);
        bf[ni] = *(const short8*)(lds_b + row * 64 + phys * 8);
      }
#pragma unroll
      for (int mi = 0; mi < 4; ++mi)
#pragma unroll
        for (int ni = 0; ni < 4; ++ni)
          acc[mi][ni] = __builtin_amdgcn_mfma_f32_16x16x32_bf16(af[mi], bf[ni],
                                                                acc[mi][ni], 0, 0, 0);
    }
  }

  // epilogue. C layout: row = quad*4+reg, col = ln15 (per 16x16 tile)
#pragma unroll
  for (int mi = 0; mi < 4; ++mi) {
#pragma unroll
    for (int ni = 0; ni < 4; ++ni) {
      int n = n0 + wc * 64 + ni * 16 + ln15;
      float bv = bias[n];
      int mbase = m0 + wr * 64 + mi * 16 + quad * 4;
      if (MODE == 0) {
        int h = n >> 7, d = n & 127;
#pragma unroll
        for (int r = 0; r < 4; ++r) {
          int m = mbase + r;
          int b = m >> 11, t = m & 2047;
          ((unsigned short*)Cout)[((((long)(b * 16 + h)) << 11) + t) * 128 + d] =
              f2bf(acc[mi][ni][r] + bv);
        }
      } else if (MODE == 1) {
        int h = n >> 7, d = n & 127;
        int b = mbase >> 11, t = mbase & 2047;   // 4 consecutive t, same b
        ushortx4 v;
#pragma unroll
        for (int r = 0; r < 4; ++r) v[r] = f2bf(acc[mi][ni][r] + bv);
        *(ushortx4*)((unsigned short*)Cout +
                     ((((long)(b * 16 + h)) << 7) + d) * 2048 + t) = v;
      } else {
#pragma unroll
        for (int r = 0; r < 4; ++r) {
          int m = mbase + r;
          ((float*)Cout)[(long)m * 2048 + n] = acc[mi][ni][r] + bv;
        }
      }
    }
  }
}

// ---------------- flash attention (v3) ----------------
// Grid 512, 512 threads (8 waves x 32 q-rows = 256 q-rows/block).
// XCD swizzle: xcd = bid&7; bh = xcd*8 + (sl>>3); qt = sl&7. 8 q-blocks of one bh
// run near-lockstep on one XCD -> K/V stream fetched ~once per bh into L2.
// KVBLK=64. LDS (96KB, 1 block/CU): K dbuf 2x16KB | V dbuf 2x16KB | P (wave-priv) 32KB.
// Pipeline per tile t: issue stage(t+1) -> QK mfma -> softmax -> P write (no barrier,
// wave-private) -> PV mfma -> vmcnt(0) -> barrier.  One barrier per iteration.
// Epilogue: O staged in LDS (reusing K/V bufs), coalesced 16B stores.
__global__ __launch_bounds__(512, 2) void flash_kernel(
    const unsigned short* __restrict__ Q,    // [64][2048][128]
    const unsigned short* __restrict__ Kmat, // [64][2048][128]
    const unsigned short* __restrict__ Vt,   // [64][128][2048]
    unsigned short* __restrict__ Out) {      // [4][2048][2048]
  constexpr int T = 2048;
  constexpr float SCALE = 0.08838834764831845f;  // 1/sqrt(128)
  __shared__ __align__(16) unsigned short lds[49152];  // 96 KiB
  // lds[     0.. 8192) K buf 0   [64 key][128 d], 16-chunk swizzle c^(row&15)
  // lds[  8192..16384) K buf 1
  // lds[ 16384..24576) V buf 0   [128 d][64 key], 8-chunk swizzle c^(row&7)
  // lds[ 24576..32768) V buf 1
  // lds[ 32768..49152) P, wave-private 32x64 each, 8-chunk swizzle c^(row&7)

  const int tid = threadIdx.x;
  const int wave = tid >> 6, lane = tid & 63;
  const int ln15 = lane & 15, quad = lane >> 4;
  const int l7 = ln15 & 7;
  const int bid = blockIdx.x;
  const int xcd = bid & 7, sl = bid >> 3;     // sl in [0,64)
  const int bh = xcd * 8 + (sl >> 3);         // 8 bh per XCD
  const int q0 = (sl & 7) * 256;              // 8 q-tiles of 256 rows

  const unsigned short* Qb = Q + (long)bh * T * 128;
  const unsigned short* Kb = Kmat + (long)bh * T * 128;
  const unsigned short* Vb = Vt + (long)bh * 128 * T;
  unsigned short* pw = lds + 32768 + wave * 2048;   // this wave's P [32][64]

  // ---- Q tile -> registers directly (one-time 64KB read, no LDS round-trip)
  short8 qf[2][4];
#pragma unroll
  for (int mi = 0; mi < 2; ++mi)
#pragma unroll
    for (int ks = 0; ks < 4; ++ks)
      qf[mi][ks] = *(const short8*)(Qb + (long)(q0 + wave * 32 + mi * 16 + ln15) * 128 +
                                    ks * 32 + quad * 8);

  // ---- stage helper pattern (K: 1024 units, V: 1024 units; 2 each per thread)
#define STAGE_KV(t, kdst, vdst)                                                  \
  do {                                                                           \
    _Pragma("unroll") for (int j = 0; j < 2; ++j) {                              \
      int u = j * 512 + tid;                                                     \
      int row = u >> 4;                                                          \
      int c = (u & 15) ^ (row & 15);                                             \
      async_cp16(Kb + (long)((t) * 64 + row) * 128 + c * 8,                      \
                 (kdst) + (j * 512 + wave * 64) * 8);                            \
    }                                                                            \
    _Pragma("unroll") for (int j = 0; j < 2; ++j) {                              \
      int u = j * 512 + tid;                                                     \
      int row = u >> 3;                                                          \
      int c = (u & 7) ^ (row & 7);                                               \
      async_cp16(Vb + (long)row * T + (t) * 64 + c * 8,                          \
                 (vdst) + (j * 512 + wave * 64) * 8);                            \
    }                                                                            \
  } while (0)

  STAGE_KV(0, lds, lds + 16384);
  asm volatile("s_waitcnt vmcnt(0)" ::: "memory");
  __syncthreads();

  floatx4 oacc[2][8];
#pragma unroll
  for (int mi = 0; mi < 2; ++mi)
#pragma unroll
    for (int nj = 0; nj < 8; ++nj) oacc[mi][nj] = (floatx4){0.f, 0.f, 0.f, 0.f};
  float mst[2][4], lsp[2][4];   // lsp: per-LANE partial sum (reduced once at end)
#pragma unroll
  for (int mi = 0; mi < 2; ++mi)
#pragma unroll
    for (int r = 0; r < 4; ++r) { mst[mi][r] = -1e30f; lsp[mi][r] = 0.f; }

  for (int t = 0; t < 32; ++t) {
    unsigned short* kc = lds + (t & 1) * 8192;
    unsigned short* vc = lds + 16384 + (t & 1) * 8192;
    // prefetch next tile into the other buffer (overlaps with all compute below)
    if (t < 31) {
      unsigned short* kn = lds + ((t + 1) & 1) * 8192;
      unsigned short* vn = lds + 16384 + ((t + 1) & 1) * 8192;
      STAGE_KV(t + 1, kn, vn);
    }

    // ---- S = Q K^T  (A=Q frags, B=K tile; 2x4 tiles x 4 k-steps)
    floatx4 sacc[2][4];
#pragma unroll
    for (int mi = 0; mi < 2; ++mi)
#pragma unroll
      for (int ni = 0; ni < 4; ++ni) sacc[mi][ni] = (floatx4){0.f, 0.f, 0.f, 0.f};
#pragma unroll
    for (int ks = 0; ks < 4; ++ks) {
      short8 bfr[4];
#pragma unroll
      for (int ni = 0; ni < 4; ++ni) {
        int row = ni * 16 + ln15;
        int phys = (ks * 4 + quad) ^ ln15;
        bfr[ni] = *(const short8*)(kc + row * 128 + phys * 8);
      }
      __builtin_amdgcn_s_setprio(1);
#pragma unroll
      for (int mi = 0; mi < 2; ++mi)
#pragma unroll
        for (int ni = 0; ni < 4; ++ni)
          sacc[mi][ni] = __builtin_amdgcn_mfma_f32_16x16x32_bf16(qf[mi][ks], bfr[ni],
                                                                 sacc[mi][ni], 0, 0, 0);
      __builtin_amdgcn_s_setprio(0);
    }

    // ---- online softmax (row = quad*4+r; 16 lanes x 4 ni hold the 64 keys)
#pragma unroll
    for (int mi = 0; mi < 2; ++mi)
#pragma unroll
      for (int r = 0; r < 4; ++r) {
        float mx = fmaxf(fmaxf(sacc[mi][0][r], sacc[mi][1][r]),
                         fmaxf(sacc[mi][2][r], sacc[mi][3][r]));
#pragma unroll
        for (int off = 1; off < 16; off <<= 1) mx = fmaxf(mx, __shfl_xor(mx, off, 16));
        mx *= SCALE;
        float mold = mst[mi][r];
        float mnew = fmaxf(mold, mx);
        float alpha = __expf(mold - mnew);
        float rs = 0.f;
#pragma unroll
        for (int ni = 0; ni < 4; ++ni) {
          float p = __expf(sacc[mi][ni][r] * SCALE - mnew);
          sacc[mi][ni][r] = p;
          rs += p;
        }
        mst[mi][r] = mnew;
        lsp[mi][r] = lsp[mi][r] * alpha + rs;   // per-lane partial, no shuffle
#pragma unroll
        for (int nj = 0; nj < 8; ++nj) oacc[mi][nj][r] *= alpha;
      }

    // ---- write P (bf16) into wave-private buffer: no barrier needed
#pragma unroll
    for (int mi = 0; mi < 2; ++mi)
#pragma unroll
      for (int ni = 0; ni < 4; ++ni) {
        int cc = ni * 2 + (ln15 >> 3);
#pragma unroll
        for (int r = 0; r < 4; ++r) {
          int m = mi * 16 + quad * 4 + r;
          pw[m * 64 + (cc ^ (m & 7)) * 8 + l7] = f2bf(sacc[mi][ni][r]);
        }
      }

    // ---- O += P V  (A=P from pbuf, B=V tile; 2 k-steps of 32 keys)
#pragma unroll
    for (int ks = 0; ks < 2; ++ks) {
      short8 af[2], bv[8];
#pragma unroll
      for (int mi = 0; mi < 2; ++mi) {
        int phys = (ks * 4 + quad) ^ l7;
        af[mi] = *(const short8*)(pw + (mi * 16 + ln15) * 64 + phys * 8);
      }
#pragma unroll
      for (int nj = 0; nj < 8; ++nj) {
        int row = nj * 16 + ln15;
        int phys = (ks * 4 + quad) ^ (row & 7);
        bv[nj] = *(const short8*)(vc + row * 64 + phys * 8);
      }
      __builtin_amdgcn_s_setprio(1);
#pragma unroll
      for (int mi = 0; mi < 2; ++mi)
#pragma unroll
        for (int nj = 0; nj < 8; ++nj)
          oacc[mi][nj] = __builtin_amdgcn_mfma_f32_16x16x32_bf16(af[mi], bv[nj],
                                                                 oacc[mi][nj], 0, 0, 0);
      __builtin_amdgcn_s_setprio(0);
    }

    // next buffer must be resident before anyone reads it next iter
    asm volatile("s_waitcnt vmcnt(0)" ::: "memory");
    __syncthreads();
  }
#undef STAGE_KV

  // ---- epilogue: finish l-sum reduce, normalize, stage O in LDS, coalesced store
  float rinv[2][4];
#pragma unroll
  for (int mi = 0; mi < 2; ++mi)
#pragma unroll
    for (int r = 0; r < 4; ++r) {
      float l = lsp[mi][r];
#pragma unroll
      for (int off = 1; off < 16; off <<= 1) l += __shfl_xor(l, off, 16);
      rinv[mi][r] = 1.f / l;
    }
  // O tile [256 rows][128 cols] bf16 = 64KB staged over the K/V buffers
#pragma unroll
  for (int mi = 0; mi < 2; ++mi)
#pragma unroll
    for (int nj = 0; nj < 8; ++nj)
#pragma unroll
      for (int r = 0; r < 4; ++r)
        lds[(wave * 32 + mi * 16 + quad * 4 + r) * 128 + nj * 16 + ln15] =
            f2bf(oacc[mi][nj][r] * rinv[mi][r]);
  __syncthreads();
  const int b = bh >> 4, h = bh & 15;
  long obase = ((long)(b * T + q0) << 11) + h * 128;
#pragma unroll
  for (int j = 0; j < 8; ++j) {   // 4096 16B units / 512 threads
    int u = j * 512 + tid;
    int r = u >> 4, c = u & 15;
    *(short8*)(Out + obase + ((long)r << 11) + c * 8) =
        *(const short8*)(lds + r * 128 + c * 8);
  }
}

extern "C" void kernel_launch(void* const* d_in, const int* in_sizes, int n_in,
                              void* d_out, int out_size, void* d_ws, size_t ws_size,
                              hipStream_t stream) {
  const float* x    = (const float*)d_in[0];
  const float* pos  = (const float*)d_in[1];
  const float* wq_w = (const float*)d_in[2];
  const float* wq_b = (const float*)d_in[3];
  const float* wk_w = (const float*)d_in[4];
  const float* wk_b = (const float*)d_in[5];
  const float* wv_w = (const float*)d_in[6];
  const float* wv_b = (const float*)d_in[7];
  const float* wo_w = (const float*)d_in[8];
  const float* wo_b = (const float*)d_in[9];

  unsigned short* xb  = (unsigned short*)d_ws;
  unsigned short* wqb = xb  + (1u << 24);
  unsigned short* wkb = wqb + (1u << 22);
  unsigned short* wvb = wkb + (1u << 22);
  unsigned short* wob = wvb + (1u << 22);
  unsigned short* qb  = wob + (1u << 22);
  unsigned short* kb  = qb  + (1u << 24);
  unsigned short* vtb = kb  + (1u << 24);
  unsigned short* ab  = vtb + (1u << 24);   // attention output, bf16 [8192][2048]

  cast_kernel<<<16384, 256, 0, stream>>>((const float4*)x, (ushortx4*)xb);
  cast_kernel<<<4096, 256, 0, stream>>>((const float4*)wq_w, (ushortx4*)wqb);
  cast_kernel<<<4096, 256, 0, stream>>>((const float4*)wk_w, (ushortx4*)wkb);
  cast_kernel<<<4096, 256, 0, stream>>>((const float4*)wv_w, (ushortx4*)wvb);
  cast_kernel<<<4096, 256, 0, stream>>>((const float4*)wo_w, (ushortx4*)wob);

  gemm_bt<0><<<1024, 256, 0, stream>>>(xb, wqb, wq_b, (void*)qb);
  gemm_bt<0><<<1024, 256, 0, stream>>>(xb, wkb, wk_b, (void*)kb);
  gemm_bt<1><<<1024, 256, 0, stream>>>(xb, wvb, wv_b, (void*)vtb);
  rope_kernel<<<65536, 256, 0, stream>>>(qb, kb, pos);
  flash_kernel<<<512, 512, 0, stream>>>(qb, kb, vtb, ab);
  gemm_bt<2><<<1024, 256, 0, stream>>>(ab, wob, wo_b, d_out);
}

// Round 3
// 697.738 us; speedup vs baseline: 2.0046x; 1.0726x over previous
//
#include <hip/hip_runtime.h>

// Attention (B=4, T=2048, dim=2048, H=16, hd=128) on gfx950.
// Pipeline: cast->bf16 | QKV gemms (MFMA, A*B^T) | RoPE | flash attention | out gemm.
// R5: fix R4's half-staged GEMM tile (each thread now stages 2x16B per array per
//     K-tile = full 1024-unit coverage; vmcnt counts 4/stage). Schedule unchanged:
//     256x256 tile, BK=32, 8 waves, triple-buffered LDS, counted vmcnt, raw s_barrier,
//     LDS-restaged coalesced epilogues. Flash unchanged from R3 (252us verified).
// Workspace layout (needs 192 MiB):
//   xb[2^24] wqb wkb wvb wob[2^22 each] qb[2^24] kb[2^24] vtb[2^24] aout[2^24]  (all bf16)

using floatx4  = __attribute__((ext_vector_type(4))) float;
using short8   = __attribute__((ext_vector_type(8))) short;
using ushortx4 = __attribute__((ext_vector_type(4))) unsigned short;

#define DEVFN static __device__ __forceinline__

DEVFN unsigned short f2bf(float f) {          // RNE float->bf16
  unsigned u = __builtin_bit_cast(unsigned, f);
  u += 0x7fffu + ((u >> 16) & 1u);
  return (unsigned short)(u >> 16);
}
DEVFN float bf2f(unsigned short h) {
  return __builtin_bit_cast(float, ((unsigned)h) << 16);
}

DEVFN void async_cp16(const unsigned short* g, unsigned short* l) {
  __builtin_amdgcn_global_load_lds(
      (const __attribute__((address_space(1))) void*)g,
      (__attribute__((address_space(3))) void*)l,
      16, 0, 0);
}

// ---------------- cast fp32 -> bf16 (vectorized) ----------------
__global__ __launch_bounds__(256) void cast_kernel(const float4* __restrict__ in,
                                                   ushortx4* __restrict__ out) {
  long u = (long)blockIdx.x * 256 + threadIdx.x;
  float4 v = in[u];
  out[u] = (ushortx4){f2bf(v.x), f2bf(v.y), f2bf(v.z), f2bf(v.w)};
}

// ---------------- RoPE in-place on Q,K [64][2048][128] bf16 ----------------
__global__ __launch_bounds__(256) void rope_kernel(unsigned short* __restrict__ Q,
                                                   unsigned short* __restrict__ K,
                                                   const float* __restrict__ pos) {
  long idx = (long)blockIdx.x * 256 + threadIdx.x;   // 2^24 threads
  unsigned short* arr = (idx >> 23) ? K : Q;
  long rem = idx & ((1L << 23) - 1);
  long row = rem >> 6;          // bh*2048 + t
  int j = (int)(rem & 63);      // pair index 0..63
  int t = (int)(row & 2047);
  // freq_j = 10000^(-j/64) = exp2(-j * log2(10000)/64)
  float ang = pos[t] * exp2f(-0.20762051f * (float)j);
  float s = sinf(ang), c = cosf(ang);
  unsigned short* base = arr + (row << 7);
  float x1 = bf2f(base[j]), x2 = bf2f(base[j + 64]);
  base[j]      = f2bf(x1 * c - x2 * s);
  base[j + 64] = f2bf(x2 * c + x1 * s);
}

// ---------------- GEMM: C[m,n] = sum_k A[m,k]*B[n,k] + bias[n] ----------------
// M=8192 N=2048 K=2048. 256x256 tile, BK=32, 8 waves (wm=wave>>2, wn=wave&3),
// per-wave output 128x64 = acc[8][4] of 16x16 frags. mfma 16x16x32.
// Grid 256 (1 block/CU), XCD swizzle: m-tile = (bid&7)*4 + (sl&3), n-tile = sl>>2.
// Triple-buffered LDS K-tiles (3 x (A 16KB + B 16KB) = 96KB): stage tile t+2 while
// computing t; s_waitcnt vmcnt(4) + raw s_barrier per tile -> loads in flight across
// 2 tile-computes, no drain in steady state (T3+T4).
// LDS swizzle (both-sides): 128B line L = rows {2L,2L+1}; logical chunk cc =
// (row&1)*4 + kcol; phys = cc ^ (L&7). Stage: linear LDS dst + inverse-swizzled
// global src. Read: ds_read_b128, 8 lanes fully cover each 128B line -> conflict-free.
// Epilogue: all MODEs restage C through LDS, 16B/lane coalesced global stores.
// MODE 0: bf16 out [B,H,T,hd] | MODE 1: bf16 out [B,H,hd,T] | MODE 2: fp32 out [M,N].
template <int MODE>
__global__ __launch_bounds__(512, 2) void gemm_bt(const unsigned short* __restrict__ A,
                                                  const unsigned short* __restrict__ Bw,
                                                  const float* __restrict__ bias,
                                                  void* __restrict__ Cout) {
  constexpr int K = 2048;
  constexpr int NT = 64;                         // K-tiles of 32
  __shared__ __align__(16) unsigned short lds[49152];   // 96 KiB: 3 bufs x 16384 shorts
  const int tid = threadIdx.x;
  const int wave = tid >> 6, lane = tid & 63;
  const int ln15 = lane & 15, quad = lane >> 4;
  const int wm = wave >> 2, wn = wave & 3;
  const int bid = blockIdx.x;
  const int xcd = bid & 7, sl = bid >> 3;        // sl in [0,32)
  const int m0 = (xcd * 4 + (sl & 3)) * 256;     // 4 m-tiles per XCD
  const int n0 = (sl >> 2) * 256;                // 8 n-tiles

  // ---- per-thread stage sources (inverse-swizzled global addr, linear LDS dst)
  // unit u covers lds shorts [u*8, u*8+8); L = u>>3, phys p = u&7, cc = p ^ (L&7),
  // row = 2L + (cc>>2), col = (cc&3)*8.  Thread stages units tid and tid+512.
  const unsigned short* srcA0;
  const unsigned short* srcA1;
  const unsigned short* srcB0;
  const unsigned short* srcB1;
  {
    int u = tid;
    int L = u >> 3, cc = (u & 7) ^ (L & 7);
    int row = L * 2 + (cc >> 2), col = (cc & 3) * 8;
    srcA0 = A + (long)(m0 + row) * K + col;
    srcB0 = Bw + (long)(n0 + row) * K + col;
  }
  {
    int u = tid + 512;
    int L = u >> 3, cc = (u & 7) ^ (L & 7);
    int row = L * 2 + (cc >> 2), col = (cc & 3) * 8;
    srcA1 = A + (long)(m0 + row) * K + col;
    srcB1 = Bw + (long)(n0 + row) * K + col;
  }
  const int sdst = wave * 512;          // shorts: wave-uniform base (+lane*16B by HW)

#define STAGE_G(t, bufp)                                                \
  do {                                                                  \
    async_cp16(srcA0 + (long)(t) * 32, (bufp) + sdst);                  \
    async_cp16(srcA1 + (long)(t) * 32, (bufp) + 4096 + sdst);           \
    async_cp16(srcB0 + (long)(t) * 32, (bufp) + 8192 + sdst);           \
    async_cp16(srcB1 + (long)(t) * 32, (bufp) + 12288 + sdst);          \
  } while (0)

  // ---- per-thread LDS read offsets (loop-invariant)
  int offA[8], offB[4];
#pragma unroll
  for (int mi = 0; mi < 8; ++mi) {
    int row = wm * 128 + mi * 16 + ln15;
    int line = row >> 1, cc = (row & 1) * 4 + quad;
    offA[mi] = line * 64 + (cc ^ (line & 7)) * 8;
  }
#pragma unroll
  for (int nj = 0; nj < 4; ++nj) {
    int row = wn * 64 + nj * 16 + ln15;
    int line = row >> 1, cc = (row & 1) * 4 + quad;
    offB[nj] = 8192 + line * 64 + (cc ^ (line & 7)) * 8;
  }

  floatx4 acc[8][4];
#pragma unroll
  for (int i = 0; i < 8; ++i)
#pragma unroll
    for (int j = 0; j < 4; ++j) acc[i][j] = (floatx4){0.f, 0.f, 0.f, 0.f};

  unsigned short* const bA0 = lds;
  unsigned short* const bA1 = lds + 16384;
  unsigned short* const bA2 = lds + 32768;

  STAGE_G(0, bA0);
  STAGE_G(1, bA1);
  asm volatile("s_waitcnt vmcnt(4)" ::: "memory");
  __builtin_amdgcn_s_barrier();

  int cb = 0;
  for (int t = 0; t < NT; ++t) {
    unsigned short* cur = (cb == 0) ? bA0 : ((cb == 1) ? bA1 : bA2);
    if (t < NT - 2) {
      int nb = cb ? cb - 1 : 2;                  // (cb+2)%3
      unsigned short* nxt = (nb == 0) ? bA0 : ((nb == 1) ? bA1 : bA2);
      STAGE_G(t + 2, nxt);
    }
    short8 af[8], bf4[4];
#pragma unroll
    for (int mi = 0; mi < 8; ++mi) af[mi] = *(const short8*)(cur + offA[mi]);
#pragma unroll
    for (int nj = 0; nj < 4; ++nj) bf4[nj] = *(const short8*)(cur + offB[nj]);
    __builtin_amdgcn_s_setprio(1);
#pragma unroll
    for (int mi = 0; mi < 8; ++mi)
#pragma unroll
      for (int nj = 0; nj < 4; ++nj)
        acc[mi][nj] = __builtin_amdgcn_mfma_f32_16x16x32_bf16(af[mi], bf4[nj],
                                                              acc[mi][nj], 0, 0, 0);
    __builtin_amdgcn_s_setprio(0);
    if (t < NT - 2) {
      asm volatile("s_waitcnt vmcnt(4)" ::: "memory");
    } else if (t == NT - 2) {
      asm volatile("s_waitcnt vmcnt(0)" ::: "memory");
    }
    __builtin_amdgcn_s_barrier();
    cb = (cb == 2) ? 0 : cb + 1;
  }
#undef STAGE_G

  // ---- epilogue: restage C tile through LDS, coalesced 16B stores ----
  const int b_ = m0 >> 11;               // batch (m-tile never crosses b boundary)
  const int t0m = m0 & 2047;
  const int h0 = n0 >> 7;                // two heads h0, h0+1 in this n-tile

  if (MODE == 0) {
    // out [b][h][t][d]: LDS [128 tl][256 n], chunk c=n>>3 (32), phys = c ^ (tl&15)
#pragma unroll
    for (int rnd = 0; rnd < 2; ++rnd) {
      __syncthreads();
      if (wm == rnd) {
#pragma unroll
        for (int nj = 0; nj < 4; ++nj) {
          int nloc = wn * 64 + nj * 16 + ln15;
          float bv = bias[n0 + nloc];
#pragma unroll
          for (int mi = 0; mi < 8; ++mi)
#pragma unroll
            for (int r = 0; r < 4; ++r) {
              int tl = mi * 16 + quad * 4 + r;
              int phys = (nloc >> 3) ^ (tl & 15);
              lds[tl * 256 + phys * 8 + (nloc & 7)] = f2bf(acc[mi][nj][r] + bv);
            }
        }
      }
      __syncthreads();
#pragma unroll
      for (int j = 0; j < 8; ++j) {
        int u = j * 512 + tid;
        int tl = u >> 5, c = u & 31;
        int phys = c ^ (tl & 15);
        int h = h0 + (c >> 4);
        int tt = t0m + rnd * 128 + tl;
        *(short8*)((unsigned short*)Cout +
                   ((((long)(b_ * 16 + h)) << 11) + tt) * 128 + (c & 15) * 8) =
            *(const short8*)(lds + tl * 256 + phys * 8);
      }
    }
  } else if (MODE == 1) {
    // out [b][h][d][t]: LDS [256 n][128 tl], chunk c=tl>>3 (16), phys = c ^ (n&15)
#pragma unroll
    for (int rnd = 0; rnd < 2; ++rnd) {
      __syncthreads();
      if (wm == rnd) {
#pragma unroll
        for (int nj = 0; nj < 4; ++nj) {
          int nloc = wn * 64 + nj * 16 + ln15;
          float bv = bias[n0 + nloc];
#pragma unroll
          for (int mi = 0; mi < 8; ++mi)
#pragma unroll
            for (int r = 0; r < 4; ++r) {
              int tl = mi * 16 + quad * 4 + r;
              int phys = (tl >> 3) ^ (nloc & 15);
              lds[nloc * 128 + phys * 8 + (tl & 7)] = f2bf(acc[mi][nj][r] + bv);
            }
        }
      }
      __syncthreads();
#pragma unroll
      for (int j = 0; j < 8; ++j) {
        int u = j * 512 + tid;
        int nloc = u >> 4, c = u & 15;
        int phys = c ^ (nloc & 15);
        int h = h0 + (nloc >> 7), d = nloc & 127;
        *(short8*)((unsigned short*)Cout +
                   ((((long)(b_ * 16 + h)) << 7) + d) * 2048 + t0m + rnd * 128 + c * 8) =
            *(const short8*)(lds + nloc * 128 + phys * 8);
      }
    }
  } else {
    // fp32 out [M][N]: LDS f32 [64 tl][256 n], chunk c=n>>2 (64), phys = c ^ (tl&15)
    float* lf = (float*)lds;
#pragma unroll
    for (int rnd = 0; rnd < 4; ++rnd) {
      __syncthreads();
      if (wm == (rnd >> 1)) {
#pragma unroll
        for (int nj = 0; nj < 4; ++nj) {
          int nloc = wn * 64 + nj * 16 + ln15;
          float bv = bias[n0 + nloc];
#pragma unroll
          for (int mh = 0; mh < 4; ++mh) {
            int mi = (rnd & 1) * 4 + mh;
#pragma unroll
            for (int r = 0; r < 4; ++r) {
              int tl = mh * 16 + quad * 4 + r;
              int phys = (nloc >> 2) ^ (tl & 15);
              lf[tl * 256 + phys * 4 + (nloc & 3)] = acc[mi][nj][r] + bv;
            }
          }
        }
      }
      __syncthreads();
#pragma unroll
      for (int j = 0; j < 8; ++j) {
        int u = j * 512 + tid;
        int tl = u >> 6, c = u & 63;
        int phys = c ^ (tl & 15);
        int m = m0 + rnd * 64 + tl;
        *(floatx4*)((float*)Cout + (long)m * 2048 + n0 + c * 4) =
            *(const floatx4*)(lf + tl * 256 + phys * 4);
      }
    }
  }
}

// ---------------- flash attention (v3, unchanged from R3) ----------------
// Grid 512, 512 threads (8 waves x 32 q-rows = 256 q-rows/block).
// XCD swizzle: xcd = bid&7; bh = xcd*8 + (sl>>3); qt = sl&7.
// KVBLK=64. LDS (96KB, 1 block/CU): K dbuf 2x16KB | V dbuf 2x16KB | P (wave-priv) 32KB.
__global__ __launch_bounds__(512, 2) void flash_kernel(
    const unsigned short* __restrict__ Q,    // [64][2048][128]
    const unsigned short* __restrict__ Kmat, // [64][2048][128]
    const unsigned short* __restrict__ Vt,   // [64][128][2048]
    unsigned short* __restrict__ Out) {      // [4][2048][2048]
  constexpr int T = 2048;
  constexpr float SCALE = 0.08838834764831845f;  // 1/sqrt(128)
  __shared__ __align__(16) unsigned short lds[49152];  // 96 KiB

  const int tid = threadIdx.x;
  const int wave = tid >> 6, lane = tid & 63;
  const int ln15 = lane & 15, quad = lane >> 4;
  const int l7 = ln15 & 7;
  const int bid = blockIdx.x;
  const int xcd = bid & 7, sl = bid >> 3;     // sl in [0,64)
  const int bh = xcd * 8 + (sl >> 3);         // 8 bh per XCD
  const int q0 = (sl & 7) * 256;              // 8 q-tiles of 256 rows

  const unsigned short* Qb = Q + (long)bh * T * 128;
  const unsigned short* Kb = Kmat + (long)bh * T * 128;
  const unsigned short* Vb = Vt + (long)bh * 128 * T;
  unsigned short* pw = lds + 32768 + wave * 2048;   // this wave's P [32][64]

  // ---- Q tile -> registers directly
  short8 qf[2][4];
#pragma unroll
  for (int mi = 0; mi < 2; ++mi)
#pragma unroll
    for (int ks = 0; ks < 4; ++ks)
      qf[mi][ks] = *(const short8*)(Qb + (long)(q0 + wave * 32 + mi * 16 + ln15) * 128 +
                                    ks * 32 + quad * 8);

#define STAGE_KV(t, kdst, vdst)                                                  \
  do {                                                                           \
    _Pragma("unroll") for (int j = 0; j < 2; ++j) {                              \
      int u = j * 512 + tid;                                                     \
      int row = u >> 4;                                                          \
      int c = (u & 15) ^ (row & 15);                                             \
      async_cp16(Kb + (long)((t) * 64 + row) * 128 + c * 8,                      \
                 (kdst) + (j * 512 + wave * 64) * 8);                            \
    }                                                                            \
    _Pragma("unroll") for (int j = 0; j < 2; ++j) {                              \
      int u = j * 512 + tid;                                                     \
      int row = u >> 3;                                                          \
      int c = (u & 7) ^ (row & 7);                                               \
      async_cp16(Vb + (long)row * T + (t) * 64 + c * 8,                          \
                 (vdst) + (j * 512 + wave * 64) * 8);                            \
    }                                                                            \
  } while (0)

  STAGE_KV(0, lds, lds + 16384);
  asm volatile("s_waitcnt vmcnt(0)" ::: "memory");
  __syncthreads();

  floatx4 oacc[2][8];
#pragma unroll
  for (int mi = 0; mi < 2; ++mi)
#pragma unroll
    for (int nj = 0; nj < 8; ++nj) oacc[mi][nj] = (floatx4){0.f, 0.f, 0.f, 0.f};
  float mst[2][4], lsp[2][4];
#pragma unroll
  for (int mi = 0; mi < 2; ++mi)
#pragma unroll
    for (int r = 0; r < 4; ++r) { mst[mi][r] = -1e30f; lsp[mi][r] = 0.f; }

  for (int t = 0; t < 32; ++t) {
    unsigned short* kc = lds + (t & 1) * 8192;
    unsigned short* vc = lds + 16384 + (t & 1) * 8192;
    if (t < 31) {
      unsigned short* kn = lds + ((t + 1) & 1) * 8192;
      unsigned short* vn = lds + 16384 + ((t + 1) & 1) * 8192;
      STAGE_KV(t + 1, kn, vn);
    }

    floatx4 sacc[2][4];
#pragma unroll
    for (int mi = 0; mi < 2; ++mi)
#pragma unroll
      for (int ni = 0; ni < 4; ++ni) sacc[mi][ni] = (floatx4){0.f, 0.f, 0.f, 0.f};
#pragma unroll
    for (int ks = 0; ks < 4; ++ks) {
      short8 bfr[4];
#pragma unroll
      for (int ni = 0; ni < 4; ++ni) {
        int row = ni * 16 + ln15;
        int phys = (ks * 4 + quad) ^ ln15;
        bfr[ni] = *(const short8*)(kc + row * 128 + phys * 8);
      }
      __builtin_amdgcn_s_setprio(1);
#pragma unroll
      for (int mi = 0; mi < 2; ++mi)
#pragma unroll
        for (int ni = 0; ni < 4; ++ni)
          sacc[mi][ni] = __builtin_amdgcn_mfma_f32_16x16x32_bf16(qf[mi][ks], bfr[ni],
                                                                 sacc[mi][ni], 0, 0, 0);
      __builtin_amdgcn_s_setprio(0);
    }

#pragma unroll
    for (int mi = 0; mi < 2; ++mi)
#pragma unroll
      for (int r = 0; r < 4; ++r) {
        float mx = fmaxf(fmaxf(sacc[mi][0][r], sacc[mi][1][r]),
                         fmaxf(sacc[mi][2][r], sacc[mi][3][r]));
#pragma unroll
        for (int off = 1; off < 16; off <<= 1) mx = fmaxf(mx, __shfl_xor(mx, off, 16));
        mx *= SCALE;
        float mold = mst[mi][r];
        float mnew = fmaxf(mold, mx);
        float alpha = __expf(mold - mnew);
        float rs = 0.f;
#pragma unroll
        for (int ni = 0; ni < 4; ++ni) {
          float p = __expf(sacc[mi][ni][r] * SCALE - mnew);
          sacc[mi][ni][r] = p;
          rs += p;
        }
        mst[mi][r] = mnew;
        lsp[mi][r] = lsp[mi][r] * alpha + rs;
#pragma unroll
        for (int nj = 0; nj < 8; ++nj) oacc[mi][nj][r] *= alpha;
      }

#pragma unroll
    for (int mi = 0; mi < 2; ++mi)
#pragma unroll
      for (int ni = 0; ni < 4; ++ni) {
        int cc = ni * 2 + (ln15 >> 3);
#pragma unroll
        for (int r = 0; r < 4; ++r) {
          int m = mi * 16 + quad * 4 + r;
          pw[m * 64 + (cc ^ (m & 7)) * 8 + l7] = f2bf(sacc[mi][ni][r]);
        }
      }

#pragma unroll
    for (int ks = 0; ks < 2; ++ks) {
      short8 af[2], bv[8];
#pragma unroll
      for (int mi = 0; mi < 2; ++mi) {
        int phys = (ks * 4 + quad) ^ l7;
        af[mi] = *(const short8*)(pw + (mi * 16 + ln15) * 64 + phys * 8);
      }
#pragma unroll
      for (int nj = 0; nj < 8; ++nj) {
        int row = nj * 16 + ln15;
        int phys = (ks * 4 + quad) ^ (row & 7);
        bv[nj] = *(const short8*)(vc + row * 64 + phys * 8);
      }
      __builtin_amdgcn_s_setprio(1);
#pragma unroll
      for (int mi = 0; mi < 2; ++mi)
#pragma unroll
        for (int nj = 0; nj < 8; ++nj)
          oacc[mi][nj] = __builtin_amdgcn_mfma_f32_16x16x32_bf16(af[mi], bv[nj],
                                                                 oacc[mi][nj], 0, 0, 0);
      __builtin_amdgcn_s_setprio(0);
    }

    asm volatile("s_waitcnt vmcnt(0)" ::: "memory");
    __syncthreads();
  }
#undef STAGE_KV

  float rinv[2][4];
#pragma unroll
  for (int mi = 0; mi < 2; ++mi)
#pragma unroll
    for (int r = 0; r < 4; ++r) {
      float l = lsp[mi][r];
#pragma unroll
      for (int off = 1; off < 16; off <<= 1) l += __shfl_xor(l, off, 16);
      rinv[mi][r] = 1.f / l;
    }
#pragma unroll
  for (int mi = 0; mi < 2; ++mi)
#pragma unroll
    for (int nj = 0; nj < 8; ++nj)
#pragma unroll
      for (int r = 0; r < 4; ++r)
        lds[(wave * 32 + mi * 16 + quad * 4 + r) * 128 + nj * 16 + ln15] =
            f2bf(oacc[mi][nj][r] * rinv[mi][r]);
  __syncthreads();
  const int b = bh >> 4, h = bh & 15;
  long obase = ((long)(b * T + q0) << 11) + h * 128;
#pragma unroll
  for (int j = 0; j < 8; ++j) {
    int u = j * 512 + tid;
    int r = u >> 4, c = u & 15;
    *(short8*)(Out + obase + ((long)r << 11) + c * 8) =
        *(const short8*)(lds + r * 128 + c * 8);
  }
}

extern "C" void kernel_launch(void* const* d_in, const int* in_sizes, int n_in,
                              void* d_out, int out_size, void* d_ws, size_t ws_size,
                              hipStream_t stream) {
  const float* x    = (const float*)d_in[0];
  const float* pos  = (const float*)d_in[1];
  const float* wq_w = (const float*)d_in[2];
  const float* wq_b = (const float*)d_in[3];
  const float* wk_w = (const float*)d_in[4];
  const float* wk_b = (const float*)d_in[5];
  const float* wv_w = (const float*)d_in[6];
  const float* wv_b = (const float*)d_in[7];
  const float* wo_w = (const float*)d_in[8];
  const float* wo_b = (const float*)d_in[9];

  unsigned short* xb  = (unsigned short*)d_ws;
  unsigned short* wqb = xb  + (1u << 24);
  unsigned short* wkb = wqb + (1u << 22);
  unsigned short* wvb = wkb + (1u << 22);
  unsigned short* wob = wvb + (1u << 22);
  unsigned short* qb  = wob + (1u << 22);
  unsigned short* kb  = qb  + (1u << 24);
  unsigned short* vtb = kb  + (1u << 24);
  unsigned short* ab  = vtb + (1u << 24);   // attention output, bf16 [8192][2048]

  cast_kernel<<<16384, 256, 0, stream>>>((const float4*)x, (ushortx4*)xb);
  cast_kernel<<<4096, 256, 0, stream>>>((const float4*)wq_w, (ushortx4*)wqb);
  cast_kernel<<<4096, 256, 0, stream>>>((const float4*)wk_w, (ushortx4*)wkb);
  cast_kernel<<<4096, 256, 0, stream>>>((const float4*)wv_w, (ushortx4*)wvb);
  cast_kernel<<<4096, 256, 0, stream>>>((const float4*)wo_w, (ushortx4*)wob);

  gemm_bt<0><<<256, 512, 0, stream>>>(xb, wqb, wq_b, (void*)qb);
  gemm_bt<0><<<256, 512, 0, stream>>>(xb, wkb, wk_b, (void*)kb);
  gemm_bt<1><<<256, 512, 0, stream>>>(xb, wvb, wv_b, (void*)vtb);
  rope_kernel<<<65536, 256, 0, stream>>>(qb, kb, pos);
  flash_kernel<<<512, 512, 0, stream>>>(qb, kb, vtb, ab);
  gemm_bt<2><<<256, 512, 0, stream>>>(ab, wob, wo_b, d_out);
}